// Round 7
// baseline (549.458 us; speedup 1.0000x reference)
//
#include <hip/hip_runtime.h>
#include <hip/hip_bf16.h>

#define N_NODES 100000
#define N_EDGES 800000

typedef __attribute__((ext_vector_type(8))) short short8;
typedef __attribute__((ext_vector_type(4))) float f32x4;
typedef __attribute__((ext_vector_type(2))) unsigned int u32x2;

__device__ __forceinline__ float bf2f(ushort u) {
    union { unsigned i; float f; } x; x.i = ((unsigned)u) << 16; return x.f;
}
__device__ __forceinline__ ushort f2bf(float f) {
    union { float f; unsigned u; } x { f };
    unsigned r = x.u + 0x7FFF + ((x.u >> 16) & 1);   // RNE
    return (ushort)(r >> 16);
}

// ---------------------------------------------------------------------------
// Combined prep (one launch, all independent):
//   blocks [0,384):        permute W_qkv rows + bias -> [q(128)|kv-ilv(256)]
//   blocks [384,512):      W_out -> bf16
//   blocks [512,25512):    x fp32 -> bf16 (float4 -> ushort4)
//   blocks [25512,31762):  histogram of dst + per-edge rank
// ---------------------------------------------------------------------------
__global__ __launch_bounds__(128) void prep_all(
    const float* __restrict__ Wq, const float* __restrict__ bq,
    const float* __restrict__ Wo, const float* __restrict__ x,
    const int* __restrict__ dst,
    ushort* __restrict__ Wqb, float* __restrict__ bqp, ushort* __restrict__ Wob,
    ushort* __restrict__ xb, int* __restrict__ counts, int* __restrict__ rank)
{
    int j = blockIdx.x;
    if (j < 384) {
        int h = j / 48, r = j % 48, p;
        if (r < 16)      p = h * 16 + r;
        else if (r < 32) { int d = r - 16; p = 128 + (h * 8 + (d >> 1)) * 4 + (d & 1); }
        else             { int d = r - 32; p = 128 + (h * 8 + (d >> 1)) * 4 + 2 + (d & 1); }
        Wqb[(size_t)p * 128 + threadIdx.x] = f2bf(Wq[(size_t)j * 128 + threadIdx.x]);
        if (threadIdx.x == 0) bqp[p] = bq[j];
    } else if (j < 512) {
        int j2 = j - 384;
        Wob[(size_t)j2 * 128 + threadIdx.x] = f2bf(Wo[(size_t)j2 * 128 + threadIdx.x]);
    } else if (j < 25512) {
        int i = (j - 512) * 128 + threadIdx.x;   // float4 index, 3.2M total
        float4 v = reinterpret_cast<const float4*>(x)[i];
        ushort4 o;
        o.x = f2bf(v.x); o.y = f2bf(v.y); o.z = f2bf(v.z); o.w = f2bf(v.w);
        reinterpret_cast<ushort4*>(xb)[i] = o;
    } else {
        int e = (j - 25512) * 128 + threadIdx.x;
        if (e < N_EDGES) rank[e] = atomicAdd(&counts[dst[e]], 1);
    }
}

// ---------------------------------------------------------------------------
// MFMA GEMM: C[M x Ncols] = A(bf16 M x 128) @ B(bf16 Ncols x 128)^T + bias.
// Tile 128x128, 4 waves, 4x4 frags of mfma_f32_16x16x32_bf16, BK=64,
// LDS pad 72. Grid: x = col block (fast) so col-tiles sharing an A row-tile
// are dispatch-adjacent (A re-reads hit L2/L3).
// SWAPPED operands: mfma(b_frag, a_frag) -> each lane holds 4 consecutive
// cols per frag -> packed 8B/16B stores.
// ---------------------------------------------------------------------------
template<int OUT_BF16>
__global__ __launch_bounds__(256) void gemm_mfma(
    const ushort* __restrict__ A, const ushort* __restrict__ B,
    const float* __restrict__ bias, void* __restrict__ Cv,
    int M, int ldc)
{
    __shared__ ushort As[128][72];
    __shared__ ushort Bs[128][72];
    const int t = threadIdx.x;
    const int lane = t & 63;
    const int w = t >> 6;
    const int wm = w >> 1, wn = w & 1;
    const int n0 = blockIdx.y * 128;   // rows (slow)
    const int j0 = blockIdx.x * 128;   // cols (fast)

    f32x4 acc[4][4];
    #pragma unroll
    for (int i = 0; i < 4; ++i)
        #pragma unroll
        for (int j = 0; j < 4; ++j) acc[i][j] = (f32x4){0.f, 0.f, 0.f, 0.f};

    for (int kb = 0; kb < 128; kb += 64) {
        #pragma unroll
        for (int it = 0; it < 4; ++it) {
            int c = it * 256 + t;
            int row = c >> 3, g = c & 7;
            int ar = n0 + row; if (ar >= M) ar = M - 1;   // stores guarded
            *reinterpret_cast<short8*>(&As[row][g * 8]) =
                *reinterpret_cast<const short8*>(A + (size_t)ar * 128 + kb + g * 8);
            *reinterpret_cast<short8*>(&Bs[row][g * 8]) =
                *reinterpret_cast<const short8*>(B + (size_t)(j0 + row) * 128 + kb + g * 8);
        }
        __syncthreads();
        #pragma unroll
        for (int kf = 0; kf < 2; ++kf) {
            short8 af[4], bfr[4];
            #pragma unroll
            for (int mf = 0; mf < 4; ++mf)
                af[mf] = *reinterpret_cast<const short8*>(
                    &As[wm * 64 + mf * 16 + (lane & 15)][kf * 32 + (lane >> 4) * 8]);
            #pragma unroll
            for (int nf = 0; nf < 4; ++nf)
                bfr[nf] = *reinterpret_cast<const short8*>(
                    &Bs[wn * 64 + nf * 16 + (lane & 15)][kf * 32 + (lane >> 4) * 8]);
            #pragma unroll
            for (int mf = 0; mf < 4; ++mf)
                #pragma unroll
                for (int nf = 0; nf < 4; ++nf)
                    acc[mf][nf] = __builtin_amdgcn_mfma_f32_16x16x32_bf16(
                        bfr[nf], af[mf], acc[mf][nf], 0, 0, 0);   // SWAPPED
        }
        __syncthreads();
    }

    const int r = lane & 15, c4 = (lane >> 4) * 4;
    #pragma unroll
    for (int mf = 0; mf < 4; ++mf) {
        int row = n0 + wm * 64 + mf * 16 + r;
        if (row >= M) continue;
        #pragma unroll
        for (int nf = 0; nf < 4; ++nf) {
            int col = j0 + wn * 64 + nf * 16 + c4;
            f32x4 a = acc[mf][nf];
            float v0 = a[0] + bias[col],     v1 = a[1] + bias[col + 1];
            float v2 = a[2] + bias[col + 2], v3 = a[3] + bias[col + 3];
            if (OUT_BF16) {
                u32x2 u;
                u[0] = (unsigned)f2bf(v0) | ((unsigned)f2bf(v1) << 16);
                u[1] = (unsigned)f2bf(v2) | ((unsigned)f2bf(v3) << 16);
                *reinterpret_cast<u32x2*>((ushort*)Cv + (size_t)row * ldc + col) = u;
            } else {
                float4 o = {v0, v1, v2, v3};
                *reinterpret_cast<float4*>((float*)Cv + (size_t)row * ldc + col) = o;
            }
        }
    }
}

// ---------------------------------------------------------------------------
// Single-block exclusive scan of counts[0..N_NODES) -> row_start, + sentinel.
// 1024 threads x 98 serial elems. counts is L2-warm (just written).
// Replaces the 3-kernel scan chain (launch overhead + idle GPU).
// ---------------------------------------------------------------------------
#define CHUNK 98   // 1024*98 = 100352 >= 100000
__global__ __launch_bounds__(1024) void scan_one(
    const int* __restrict__ counts, int* __restrict__ row_start)
{
    __shared__ int sd[1024];
    const int t = threadIdx.x;
    const int base = t * CHUNK;
    int lc[CHUNK];
    int sum = 0;
    #pragma unroll 7
    for (int i = 0; i < CHUNK; ++i) {
        int idx = base + i;
        int v = (idx < N_NODES) ? counts[idx] : 0;
        lc[i] = v;
        sum += v;
    }
    sd[t] = sum; __syncthreads();
    for (int off = 1; off < 1024; off <<= 1) {
        int x = (t >= off) ? sd[t - off] : 0;
        __syncthreads();
        sd[t] += x;
        __syncthreads();
    }
    int run = sd[t] - sum;   // exclusive prefix of this chunk
    #pragma unroll 7
    for (int i = 0; i < CHUNK; ++i) {
        int idx = base + i;
        if (idx < N_NODES) row_start[idx] = run;
        run += lc[i];
    }
    if (t == 0) row_start[N_NODES] = N_EDGES;
}

// ---------------------------------------------------------------------------
// Fill CSR without atomics: position = row_start[dst] + rank (precomputed).
// ---------------------------------------------------------------------------
__global__ __launch_bounds__(256) void fill_csr(
    const int* __restrict__ src, const int* __restrict__ dst,
    const int* __restrict__ rank, const int* __restrict__ row_start,
    int* __restrict__ csr_src)
{
    int e = blockIdx.x * 256 + threadIdx.x;
    if (e >= N_EDGES) return;
    csr_src[row_start[dst[e]] + rank[e]] = src[e];
}

// ---------------------------------------------------------------------------
// Fused attention: one wave per dst node. lane l=h*8+d2 owns channels
// (h, 2d2, 2d2+1). q at node*384 + 2l (ushorts). Per edge: ONE dwordx2 at
// s*384 + 128 + 4l = [k0 k1 v0 v1]. 8-lane shfl_xor score reduce, online
// p-weighted accumulate. Unroll x4 (Poisson(8) degrees: x8 put 41% of
// edges in the serial tail and regressed — measured R6). No atomics.
// Softmax max-shift skipped (|s| bounded, shift-invariant).
// ---------------------------------------------------------------------------
__global__ __launch_bounds__(256) void fused_attn(
    const ushort* __restrict__ qkvp, const int* __restrict__ row_start,
    const int* __restrict__ csr_src, ushort* __restrict__ attnb)
{
    int node = (blockIdx.x * 256 + threadIdx.x) >> 6;
    if (node >= N_NODES) return;
    int lane = threadIdx.x & 63;

    unsigned qb = *reinterpret_cast<const unsigned*>(
        qkvp + (size_t)node * 384 + lane * 2);
    float q0 = bf2f((ushort)qb), q1 = bf2f((ushort)(qb >> 16));

    int beg = row_start[node], end = row_start[node + 1];
    float denom = 0.f, a0 = 0.f, a1 = 0.f;
    const ushort* kvbase = qkvp + 128 + lane * 4;

#define GATHER(s, u) u = *reinterpret_cast<const u32x2*>(kvbase + (size_t)(s) * 384);
#define EDGE(u) { \
        float ps = bf2f((ushort)u[0]) * q0 + bf2f((ushort)(u[0] >> 16)) * q1; \
        ps += __shfl_xor(ps, 1); \
        ps += __shfl_xor(ps, 2); \
        ps += __shfl_xor(ps, 4); \
        float p = __expf(ps * 0.25f); \
        denom += p; \
        a0 += p * bf2f((ushort)u[1]); \
        a1 += p * bf2f((ushort)(u[1] >> 16)); }

    int i = beg;
    for (; i + 4 <= end; i += 4) {
        int s0 = csr_src[i],     s1 = csr_src[i + 1];
        int s2 = csr_src[i + 2], s3 = csr_src[i + 3];
        u32x2 u0, u1, u2, u3;
        GATHER(s0, u0); GATHER(s1, u1); GATHER(s2, u2); GATHER(s3, u3);
        EDGE(u0); EDGE(u1); EDGE(u2); EDGE(u3);
    }
    for (; i < end; ++i) {
        int s = csr_src[i];
        u32x2 u;
        GATHER(s, u);
        EDGE(u);
    }
#undef GATHER
#undef EDGE

    float inv = (end > beg) ? 1.f / denom : 0.f;   // deg-0 node -> zeros
    unsigned o = ((unsigned)f2bf(a1 * inv) << 16) | (unsigned)f2bf(a0 * inv);
    *reinterpret_cast<unsigned*>(attnb + (size_t)node * 128 + lane * 2) = o;
}

// ---------------------------------------------------------------------------
// Workspace (bytes, 16B-aligned), total ~135.4 MB:
//   qkvp     [0,           76,800,000)   100000*384 bf16  [q | kv-ilv]
//   attnb    [76,800,000, 102,400,000)   100000*128 bf16
//   xb       [102,400,000,128,000,000)   100000*128 bf16
//   Wqb      [128,000,000,128,098,304)   384*128 bf16 (permuted)
//   Wob      [128,098,304,128,131,072)   128*128 bf16
//   bqp      [128,131,072,128,132,608)   384 f32 (permuted)
//   counts   [128,132,608,128,532,608)   400KB (memset 0)
//   rows     [128,532,608,128,932,624)   N+1 ints
//   rank     [128,932,624,132,132,624)   800K ints
//   csr_src  [132,132,624,135,332,624)   800K ints
// ---------------------------------------------------------------------------
extern "C" void kernel_launch(void* const* d_in, const int* in_sizes, int n_in,
                              void* d_out, int out_size, void* d_ws, size_t ws_size,
                              hipStream_t stream) {
    const float* x     = (const float*)d_in[0];
    const float* W_qkv = (const float*)d_in[1];
    const float* b_qkv = (const float*)d_in[2];
    const float* W_out = (const float*)d_in[3];
    const float* b_out = (const float*)d_in[4];
    const int*   src   = (const int*)d_in[5];
    const int*   dst   = (const int*)d_in[6];
    float* out = (float*)d_out;

    char* w = (char*)d_ws;
    ushort* qkvp     = (ushort*)(w);
    ushort* attnb    = (ushort*)(w + 76800000);
    ushort* xb       = (ushort*)(w + 102400000);
    ushort* Wqb      = (ushort*)(w + 128000000);
    ushort* Wob      = (ushort*)(w + 128098304);
    float*  bqp      = (float*)(w + 128131072);
    int*    counts   = (int*)(w + 128132608);
    int*    row_start= (int*)(w + 128532608);
    int*    rank     = (int*)(w + 128932624);
    int*    csr_src  = (int*)(w + 132132624);

    hipMemsetAsync(counts, 0, 400000, stream);

    // weights permute + W_out cvt + x cvt + dst histogram/rank (independent)
    prep_all<<<31762, 128, 0, stream>>>(W_qkv, b_qkv, W_out, x, dst,
                                        Wqb, bqp, Wob, xb, counts, rank);

    // QKV projection (bf16 A), col-block fast for A-tile reuse
    gemm_mfma<1><<<dim3(3, 782), 256, 0, stream>>>(
        xb, Wqb, bqp, (void*)qkvp, N_NODES, 384);

    scan_one<<<1, 1024, 0, stream>>>(counts, row_start);
    fill_csr<<<3125, 256, 0, stream>>>(src, dst, rank, row_start, csr_src);

    fused_attn<<<25000, 256, 0, stream>>>(qkvp, row_start, csr_src, attnb);

    gemm_mfma<0><<<dim3(1, 782), 256, 0, stream>>>(
        attnb, Wob, b_out, (void*)out, N_NODES, 128);
}

// Round 8
// 293.488 us; speedup vs baseline: 1.8722x; 1.8722x over previous
//
#include <hip/hip_runtime.h>
#include <hip/hip_bf16.h>

#define N_NODES 100000
#define N_EDGES 800000
#define NB1 98   // ceil(100000/1024)

typedef __attribute__((ext_vector_type(8))) short short8;
typedef __attribute__((ext_vector_type(4))) float f32x4;
typedef __attribute__((ext_vector_type(2))) unsigned int u32x2;

__device__ __forceinline__ float bf2f(ushort u) {
    union { unsigned i; float f; } x; x.i = ((unsigned)u) << 16; return x.f;
}
__device__ __forceinline__ ushort f2bf(float f) {
    union { float f; unsigned u; } x { f };
    unsigned r = x.u + 0x7FFF + ((x.u >> 16) & 1);   // RNE
    return (ushort)(r >> 16);
}

// ---------------------------------------------------------------------------
// Combined prep (one launch, all independent):
//   blocks [0,384):        permute W_qkv rows + bias -> [q(128)|kv-ilv(256)]
//   blocks [384,512):      W_out -> bf16
//   blocks [512,25512):    x fp32 -> bf16 (float4 -> ushort4)
//   blocks [25512,31762):  histogram of dst + per-edge rank
// ---------------------------------------------------------------------------
__global__ __launch_bounds__(128) void prep_all(
    const float* __restrict__ Wq, const float* __restrict__ bq,
    const float* __restrict__ Wo, const float* __restrict__ x,
    const int* __restrict__ dst,
    ushort* __restrict__ Wqb, float* __restrict__ bqp, ushort* __restrict__ Wob,
    ushort* __restrict__ xb, int* __restrict__ counts, int* __restrict__ rank)
{
    int j = blockIdx.x;
    if (j < 384) {
        int h = j / 48, r = j % 48, p;
        if (r < 16)      p = h * 16 + r;
        else if (r < 32) { int d = r - 16; p = 128 + (h * 8 + (d >> 1)) * 4 + (d & 1); }
        else             { int d = r - 32; p = 128 + (h * 8 + (d >> 1)) * 4 + 2 + (d & 1); }
        Wqb[(size_t)p * 128 + threadIdx.x] = f2bf(Wq[(size_t)j * 128 + threadIdx.x]);
        if (threadIdx.x == 0) bqp[p] = bq[j];
    } else if (j < 512) {
        int j2 = j - 384;
        Wob[(size_t)j2 * 128 + threadIdx.x] = f2bf(Wo[(size_t)j2 * 128 + threadIdx.x]);
    } else if (j < 25512) {
        int i = (j - 512) * 128 + threadIdx.x;   // float4 index, 3.2M total
        float4 v = reinterpret_cast<const float4*>(x)[i];
        ushort4 o;
        o.x = f2bf(v.x); o.y = f2bf(v.y); o.z = f2bf(v.z); o.w = f2bf(v.w);
        reinterpret_cast<ushort4*>(xb)[i] = o;
    } else {
        int e = (j - 25512) * 128 + threadIdx.x;
        if (e < N_EDGES) rank[e] = atomicAdd(&counts[dst[e]], 1);
    }
}

// ---------------------------------------------------------------------------
// MFMA GEMM: C[M x Ncols] = A(bf16 M x 128) @ B(bf16 Ncols x 128)^T + bias.
// Tile 128x128, 4 waves, 4x4 frags of mfma_f32_16x16x32_bf16, BK=64,
// LDS pad 72. Grid: x = col block (fast) so col-tiles sharing an A row-tile
// are dispatch-adjacent (A re-reads hit L2/L3).
// SWAPPED operands: mfma(b_frag, a_frag) -> each lane holds 4 consecutive
// cols per frag -> packed 8B/16B stores.
// ---------------------------------------------------------------------------
template<int OUT_BF16>
__global__ __launch_bounds__(256) void gemm_mfma(
    const ushort* __restrict__ A, const ushort* __restrict__ B,
    const float* __restrict__ bias, void* __restrict__ Cv,
    int M, int ldc)
{
    __shared__ ushort As[128][72];
    __shared__ ushort Bs[128][72];
    const int t = threadIdx.x;
    const int lane = t & 63;
    const int w = t >> 6;
    const int wm = w >> 1, wn = w & 1;
    const int n0 = blockIdx.y * 128;   // rows (slow)
    const int j0 = blockIdx.x * 128;   // cols (fast)

    f32x4 acc[4][4];
    #pragma unroll
    for (int i = 0; i < 4; ++i)
        #pragma unroll
        for (int j = 0; j < 4; ++j) acc[i][j] = (f32x4){0.f, 0.f, 0.f, 0.f};

    for (int kb = 0; kb < 128; kb += 64) {
        #pragma unroll
        for (int it = 0; it < 4; ++it) {
            int c = it * 256 + t;
            int row = c >> 3, g = c & 7;
            int ar = n0 + row; if (ar >= M) ar = M - 1;   // stores guarded
            *reinterpret_cast<short8*>(&As[row][g * 8]) =
                *reinterpret_cast<const short8*>(A + (size_t)ar * 128 + kb + g * 8);
            *reinterpret_cast<short8*>(&Bs[row][g * 8]) =
                *reinterpret_cast<const short8*>(B + (size_t)(j0 + row) * 128 + kb + g * 8);
        }
        __syncthreads();
        #pragma unroll
        for (int kf = 0; kf < 2; ++kf) {
            short8 af[4], bfr[4];
            #pragma unroll
            for (int mf = 0; mf < 4; ++mf)
                af[mf] = *reinterpret_cast<const short8*>(
                    &As[wm * 64 + mf * 16 + (lane & 15)][kf * 32 + (lane >> 4) * 8]);
            #pragma unroll
            for (int nf = 0; nf < 4; ++nf)
                bfr[nf] = *reinterpret_cast<const short8*>(
                    &Bs[wn * 64 + nf * 16 + (lane & 15)][kf * 32 + (lane >> 4) * 8]);
            #pragma unroll
            for (int mf = 0; mf < 4; ++mf)
                #pragma unroll
                for (int nf = 0; nf < 4; ++nf)
                    acc[mf][nf] = __builtin_amdgcn_mfma_f32_16x16x32_bf16(
                        bfr[nf], af[mf], acc[mf][nf], 0, 0, 0);   // SWAPPED
        }
        __syncthreads();
    }

    const int r = lane & 15, c4 = (lane >> 4) * 4;
    #pragma unroll
    for (int mf = 0; mf < 4; ++mf) {
        int row = n0 + wm * 64 + mf * 16 + r;
        if (row >= M) continue;
        #pragma unroll
        for (int nf = 0; nf < 4; ++nf) {
            int col = j0 + wn * 64 + nf * 16 + c4;
            f32x4 a = acc[mf][nf];
            float v0 = a[0] + bias[col],     v1 = a[1] + bias[col + 1];
            float v2 = a[2] + bias[col + 2], v3 = a[3] + bias[col + 3];
            if (OUT_BF16) {
                u32x2 u;
                u[0] = (unsigned)f2bf(v0) | ((unsigned)f2bf(v1) << 16);
                u[1] = (unsigned)f2bf(v2) | ((unsigned)f2bf(v3) << 16);
                *reinterpret_cast<u32x2*>((ushort*)Cv + (size_t)row * ldc + col) = u;
            } else {
                float4 o = {v0, v1, v2, v3};
                *reinterpret_cast<float4*>((float*)Cv + (size_t)row * ldc + col) = o;
            }
        }
    }
}

// ---------------------------------------------------------------------------
// scan1: 98 blocks x 1024. Coalesced loads, LDS ping-pong block scan.
// Writes block-local exclusive prefixes into row_start and bsums[b].
// (R7's single-block scan_one hit rule #20: 98-int local array -> scratch,
//  258us. This chain is scratch-free and parallel.)
// ---------------------------------------------------------------------------
__global__ __launch_bounds__(1024) void scan1(
    const int* __restrict__ counts, int* __restrict__ row_start,
    int* __restrict__ bsums)
{
    __shared__ int sd[1024];
    int t = threadIdx.x, i = blockIdx.x * 1024 + t;
    int v = (i < N_NODES) ? counts[i] : 0;
    sd[t] = v; __syncthreads();
    for (int off = 1; off < 1024; off <<= 1) {
        int x = (t >= off) ? sd[t - off] : 0;
        __syncthreads();
        sd[t] += x;
        __syncthreads();
    }
    if (i < N_NODES) row_start[i] = sd[t] - v;   // exclusive within block
    if (t == 1023) bsums[blockIdx.x] = sd[1023];
}

// ---------------------------------------------------------------------------
// scan23 (merged): every block redundantly scans the 98 bsums in LDS
// (cheap), then adds the block offset to its row_start slice. 391 blocks.
// ---------------------------------------------------------------------------
__global__ __launch_bounds__(256) void scan23(
    const int* __restrict__ bsums, int* __restrict__ row_start)
{
    __shared__ int sd[128];
    __shared__ int se[128];
    const int t = threadIdx.x;
    int v = 0;
    if (t < 128) {
        v = (t < NB1) ? bsums[t] : 0;
        sd[t] = v;
    }
    __syncthreads();
    for (int off = 1; off < 128; off <<= 1) {
        int x = (t < 128 && t >= off) ? sd[t - off] : 0;
        __syncthreads();
        if (t < 128) sd[t] += x;
        __syncthreads();
    }
    if (t < 128) se[t] = sd[t] - v;   // exclusive
    __syncthreads();
    int gid = blockIdx.x * 256 + t;
    if (gid < N_NODES) row_start[gid] += se[gid >> 10];
    if (gid == 0) row_start[N_NODES] = N_EDGES;
}

// ---------------------------------------------------------------------------
// Fill CSR without atomics: position = row_start[dst] + rank (precomputed).
// ---------------------------------------------------------------------------
__global__ __launch_bounds__(256) void fill_csr(
    const int* __restrict__ src, const int* __restrict__ dst,
    const int* __restrict__ rank, const int* __restrict__ row_start,
    int* __restrict__ csr_src)
{
    int e = blockIdx.x * 256 + threadIdx.x;
    if (e >= N_EDGES) return;
    csr_src[row_start[dst[e]] + rank[e]] = src[e];
}

// ---------------------------------------------------------------------------
// Fused attention: one wave per dst node. lane l=h*8+d2 owns channels
// (h, 2d2, 2d2+1). q at node*384 + 2l (ushorts). Per edge: ONE dwordx2 at
// s*384 + 128 + 4l = [k0 k1 v0 v1]. 8-lane shfl_xor score reduce, online
// p-weighted accumulate. Unroll x4 (Poisson(8): x8 put 41% of edges in the
// serial tail and regressed — measured R6). No atomics.
// Softmax max-shift skipped (|s| bounded, shift-invariant).
// ---------------------------------------------------------------------------
__global__ __launch_bounds__(256) void fused_attn(
    const ushort* __restrict__ qkvp, const int* __restrict__ row_start,
    const int* __restrict__ csr_src, ushort* __restrict__ attnb)
{
    int node = (blockIdx.x * 256 + threadIdx.x) >> 6;
    if (node >= N_NODES) return;
    int lane = threadIdx.x & 63;

    unsigned qb = *reinterpret_cast<const unsigned*>(
        qkvp + (size_t)node * 384 + lane * 2);
    float q0 = bf2f((ushort)qb), q1 = bf2f((ushort)(qb >> 16));

    int beg = row_start[node], end = row_start[node + 1];
    float denom = 0.f, a0 = 0.f, a1 = 0.f;
    const ushort* kvbase = qkvp + 128 + lane * 4;

#define GATHER(s, u) u = *reinterpret_cast<const u32x2*>(kvbase + (size_t)(s) * 384);
#define EDGE(u) { \
        float ps = bf2f((ushort)u[0]) * q0 + bf2f((ushort)(u[0] >> 16)) * q1; \
        ps += __shfl_xor(ps, 1); \
        ps += __shfl_xor(ps, 2); \
        ps += __shfl_xor(ps, 4); \
        float p = __expf(ps * 0.25f); \
        denom += p; \
        a0 += p * bf2f((ushort)u[1]); \
        a1 += p * bf2f((ushort)(u[1] >> 16)); }

    int i = beg;
    for (; i + 4 <= end; i += 4) {
        int s0 = csr_src[i],     s1 = csr_src[i + 1];
        int s2 = csr_src[i + 2], s3 = csr_src[i + 3];
        u32x2 u0, u1, u2, u3;
        GATHER(s0, u0); GATHER(s1, u1); GATHER(s2, u2); GATHER(s3, u3);
        EDGE(u0); EDGE(u1); EDGE(u2); EDGE(u3);
    }
    for (; i < end; ++i) {
        int s = csr_src[i];
        u32x2 u;
        GATHER(s, u);
        EDGE(u);
    }
#undef GATHER
#undef EDGE

    float inv = (end > beg) ? 1.f / denom : 0.f;   // deg-0 node -> zeros
    unsigned o = ((unsigned)f2bf(a1 * inv) << 16) | (unsigned)f2bf(a0 * inv);
    *reinterpret_cast<unsigned*>(attnb + (size_t)node * 128 + lane * 2) = o;
}

// ---------------------------------------------------------------------------
// Workspace (bytes, 16B-aligned), total ~135.4 MB:
//   qkvp     [0,           76,800,000)   100000*384 bf16  [q | kv-ilv]
//   attnb    [76,800,000, 102,400,000)   100000*128 bf16
//   xb       [102,400,000,128,000,000)   100000*128 bf16
//   Wqb      [128,000,000,128,098,304)   384*128 bf16 (permuted)
//   Wob      [128,098,304,128,131,072)   128*128 bf16
//   bqp      [128,131,072,128,132,608)   384 f32 (permuted)
//   counts   [128,132,608,128,532,608)   400KB (memset 0)
//   rows     [128,532,608,128,932,624)   N+1 ints (padded)
//   bsums    [128,932,624,128,933,024)   98 ints (padded)
//   rank     [128,933,024,132,133,024)   800K ints
//   csr_src  [132,133,024,135,333,024)   800K ints
// ---------------------------------------------------------------------------
extern "C" void kernel_launch(void* const* d_in, const int* in_sizes, int n_in,
                              void* d_out, int out_size, void* d_ws, size_t ws_size,
                              hipStream_t stream) {
    const float* x     = (const float*)d_in[0];
    const float* W_qkv = (const float*)d_in[1];
    const float* b_qkv = (const float*)d_in[2];
    const float* W_out = (const float*)d_in[3];
    const float* b_out = (const float*)d_in[4];
    const int*   src   = (const int*)d_in[5];
    const int*   dst   = (const int*)d_in[6];
    float* out = (float*)d_out;

    char* w = (char*)d_ws;
    ushort* qkvp     = (ushort*)(w);
    ushort* attnb    = (ushort*)(w + 76800000);
    ushort* xb       = (ushort*)(w + 102400000);
    ushort* Wqb      = (ushort*)(w + 128000000);
    ushort* Wob      = (ushort*)(w + 128098304);
    float*  bqp      = (float*)(w + 128131072);
    int*    counts   = (int*)(w + 128132608);
    int*    row_start= (int*)(w + 128532608);
    int*    bsums    = (int*)(w + 128932624);
    int*    rank     = (int*)(w + 128933024);
    int*    csr_src  = (int*)(w + 132133024);

    hipMemsetAsync(counts, 0, 400000, stream);

    // weights permute + W_out cvt + x cvt + dst histogram/rank (independent)
    prep_all<<<31762, 128, 0, stream>>>(W_qkv, b_qkv, W_out, x, dst,
                                        Wqb, bqp, Wob, xb, counts, rank);

    // QKV projection (bf16 A), col-block fast for A-tile reuse
    gemm_mfma<1><<<dim3(3, 782), 256, 0, stream>>>(
        xb, Wqb, bqp, (void*)qkvp, N_NODES, 384);

    scan1<<<NB1, 1024, 0, stream>>>(counts, row_start, bsums);
    scan23<<<391, 256, 0, stream>>>(bsums, row_start);
    fill_csr<<<3125, 256, 0, stream>>>(src, dst, rank, row_start, csr_src);

    fused_attn<<<25000, 256, 0, stream>>>(qkvp, row_start, csr_src, attnb);

    gemm_mfma<0><<<dim3(1, 782), 256, 0, stream>>>(
        attnb, Wob, b_out, (void*)out, N_NODES, 128);
}

// Round 10
// 281.539 us; speedup vs baseline: 1.9516x; 1.0424x over previous
//
#include <hip/hip_runtime.h>
#include <hip/hip_bf16.h>

#define N_NODES 100000
#define N_EDGES 800000
#define NB1 98   // ceil(100000/1024)

typedef __attribute__((ext_vector_type(8))) short short8;
typedef __attribute__((ext_vector_type(4))) float f32x4;
typedef __attribute__((ext_vector_type(2))) unsigned int u32x2;

__device__ __forceinline__ float bf2f(ushort u) {
    union { unsigned i; float f; } x; x.i = ((unsigned)u) << 16; return x.f;
}
__device__ __forceinline__ ushort f2bf(float f) {
    union { float f; unsigned u; } x { f };
    unsigned r = x.u + 0x7FFF + ((x.u >> 16) & 1);   // RNE
    return (ushort)(r >> 16);
}

// ---------------------------------------------------------------------------
// qkvp node-row layout (640 B): [q: 128 bf16][k: 128 fp8 e4m3][v: 128 bf16]
// channel order within each region: h*16 + d  (lane l=h*8+d2 owns d=2d2,2d2+1)
// ---------------------------------------------------------------------------

// ---------------------------------------------------------------------------
// Combined prep (one launch, independent):
//   blocks [0,384):       permute W_qkv rows + bias -> region-major cols
//   blocks [384,512):     W_out -> bf16
//   blocks [512,6762):    histogram of dst + per-edge rank
// ---------------------------------------------------------------------------
__global__ __launch_bounds__(128) void prep_all(
    const float* __restrict__ Wq, const float* __restrict__ bq,
    const float* __restrict__ Wo, const int* __restrict__ dst,
    ushort* __restrict__ Wqb, float* __restrict__ bqp, ushort* __restrict__ Wob,
    int* __restrict__ counts, int* __restrict__ rank)
{
    int j = blockIdx.x;
    if (j < 384) {
        int h = j / 48, r = j % 48, p;
        if (r < 16)      p = h * 16 + r;               // q region
        else if (r < 32) p = 128 + h * 16 + (r - 16);  // k region
        else             p = 256 + h * 16 + (r - 32);  // v region
        Wqb[(size_t)p * 128 + threadIdx.x] = f2bf(Wq[(size_t)j * 128 + threadIdx.x]);
        if (threadIdx.x == 0) bqp[p] = bq[j];
    } else if (j < 512) {
        int j2 = j - 384;
        Wob[(size_t)j2 * 128 + threadIdx.x] = f2bf(Wo[(size_t)j2 * 128 + threadIdx.x]);
    } else {
        int e = (j - 512) * 128 + threadIdx.x;
        if (e < N_EDGES) rank[e] = atomicAdd(&counts[dst[e]], 1);
    }
}

// ---------------------------------------------------------------------------
// MFMA GEMM: C = A(M x 128) @ B(bf16 Ncols x 128)^T + bias.
// A fp32 (A_F32=1, converted during LDS staging) or bf16.
// Tile 128x128, 4 waves, 4x4 frags of mfma_f32_16x16x32_bf16, BK=64,
// LDS pad 72. Grid: x = col block (fast) -> col-tiles sharing an A row-tile
// are dispatch-adjacent (A re-reads hit L2/L3).
// SWAPPED operands: mfma(b_frag, a_frag) -> lane holds 4 consecutive cols.
// MODE 0: C fp32, row stride ldc (gemm2 -> out)
// MODE 1: C = qkvp 640B rows; region by j0 (0:q bf16, 128:k fp8, 256:v bf16)
// ---------------------------------------------------------------------------
template<int A_F32, int MODE>
__global__ __launch_bounds__(256) void gemm_mfma(
    const void* __restrict__ Av, const ushort* __restrict__ B,
    const float* __restrict__ bias, void* __restrict__ Cv,
    int M, int ldc)
{
    __shared__ ushort As[128][72];
    __shared__ ushort Bs[128][72];
    const int t = threadIdx.x;
    const int lane = t & 63;
    const int w = t >> 6;
    const int wm = w >> 1, wn = w & 1;
    const int n0 = blockIdx.y * 128;   // rows (slow)
    const int j0 = blockIdx.x * 128;   // cols (fast)

    f32x4 acc[4][4];
    #pragma unroll
    for (int i = 0; i < 4; ++i)
        #pragma unroll
        for (int j = 0; j < 4; ++j) acc[i][j] = (f32x4){0.f, 0.f, 0.f, 0.f};

    for (int kb = 0; kb < 128; kb += 64) {
        #pragma unroll
        for (int it = 0; it < 4; ++it) {
            int c = it * 256 + t;
            int row = c >> 3, g = c & 7;
            int ar = n0 + row; if (ar >= M) ar = M - 1;   // stores guarded
            if (A_F32) {
                const float* ap = (const float*)Av + (size_t)ar * 128 + kb + g * 8;
                float4 a0 = *reinterpret_cast<const float4*>(ap);
                float4 a1 = *reinterpret_cast<const float4*>(ap + 4);
                short8 o;
                o[0] = (short)f2bf(a0.x); o[1] = (short)f2bf(a0.y);
                o[2] = (short)f2bf(a0.z); o[3] = (short)f2bf(a0.w);
                o[4] = (short)f2bf(a1.x); o[5] = (short)f2bf(a1.y);
                o[6] = (short)f2bf(a1.z); o[7] = (short)f2bf(a1.w);
                *reinterpret_cast<short8*>(&As[row][g * 8]) = o;
            } else {
                *reinterpret_cast<short8*>(&As[row][g * 8]) =
                    *reinterpret_cast<const short8*>(
                        (const ushort*)Av + (size_t)ar * 128 + kb + g * 8);
            }
            *reinterpret_cast<short8*>(&Bs[row][g * 8]) =
                *reinterpret_cast<const short8*>(B + (size_t)(j0 + row) * 128 + kb + g * 8);
        }
        __syncthreads();
        #pragma unroll
        for (int kf = 0; kf < 2; ++kf) {
            short8 af[4], bfr[4];
            #pragma unroll
            for (int mf = 0; mf < 4; ++mf)
                af[mf] = *reinterpret_cast<const short8*>(
                    &As[wm * 64 + mf * 16 + (lane & 15)][kf * 32 + (lane >> 4) * 8]);
            #pragma unroll
            for (int nf = 0; nf < 4; ++nf)
                bfr[nf] = *reinterpret_cast<const short8*>(
                    &Bs[wn * 64 + nf * 16 + (lane & 15)][kf * 32 + (lane >> 4) * 8]);
            #pragma unroll
            for (int mf = 0; mf < 4; ++mf)
                #pragma unroll
                for (int nf = 0; nf < 4; ++nf)
                    acc[mf][nf] = __builtin_amdgcn_mfma_f32_16x16x32_bf16(
                        bfr[nf], af[mf], acc[mf][nf], 0, 0, 0);   // SWAPPED
        }
        __syncthreads();
    }

    const int r = lane & 15, c4 = (lane >> 4) * 4;
    #pragma unroll
    for (int mf = 0; mf < 4; ++mf) {
        int row = n0 + wm * 64 + mf * 16 + r;
        if (row >= M) continue;
        #pragma unroll
        for (int nf = 0; nf < 4; ++nf) {
            int lc = wn * 64 + nf * 16 + c4;         // local col in [0,128)
            int col = j0 + lc;
            f32x4 a = acc[mf][nf];
            float v0 = a[0] + bias[col],     v1 = a[1] + bias[col + 1];
            float v2 = a[2] + bias[col + 2], v3 = a[3] + bias[col + 3];
            if (MODE == 0) {
                float4 o = {v0, v1, v2, v3};
                *reinterpret_cast<float4*>((float*)Cv + (size_t)row * ldc + col) = o;
            } else {
                char* rb = (char*)Cv + (size_t)row * 640;
                if (j0 == 128) {            // k region -> fp8 e4m3 (OCP, HW cvt)
                    int pk = __builtin_amdgcn_cvt_pk_fp8_f32(v0, v1, 0, false);
                    pk     = __builtin_amdgcn_cvt_pk_fp8_f32(v2, v3, pk, true);
                    *reinterpret_cast<int*>(rb + 256 + lc) = pk;
                } else {                    // q (off 0) / v (off 384), bf16
                    u32x2 u;
                    u[0] = (unsigned)f2bf(v0) | ((unsigned)f2bf(v1) << 16);
                    u[1] = (unsigned)f2bf(v2) | ((unsigned)f2bf(v3) << 16);
                    int off = (j0 == 0) ? lc * 2 : 384 + lc * 2;
                    *reinterpret_cast<u32x2*>(rb + off) = u;
                }
            }
        }
    }
}

// ---------------------------------------------------------------------------
// scan1: 98 blocks x 1024, LDS block scan -> block-local prefixes + bsums.
// ---------------------------------------------------------------------------
__global__ __launch_bounds__(1024) void scan1(
    const int* __restrict__ counts, int* __restrict__ row_start,
    int* __restrict__ bsums)
{
    __shared__ int sd[1024];
    int t = threadIdx.x, i = blockIdx.x * 1024 + t;
    int v = (i < N_NODES) ? counts[i] : 0;
    sd[t] = v; __syncthreads();
    for (int off = 1; off < 1024; off <<= 1) {
        int x = (t >= off) ? sd[t - off] : 0;
        __syncthreads();
        sd[t] += x;
        __syncthreads();
    }
    if (i < N_NODES) row_start[i] = sd[t] - v;   // exclusive within block
    if (t == 1023) bsums[blockIdx.x] = sd[1023];
}

// ---------------------------------------------------------------------------
// scan23: every block redundantly scans the 98 bsums in LDS, then adds the
// block offset to its row_start slice. 391 blocks.
// ---------------------------------------------------------------------------
__global__ __launch_bounds__(256) void scan23(
    const int* __restrict__ bsums, int* __restrict__ row_start)
{
    __shared__ int sd[128];
    __shared__ int se[128];
    const int t = threadIdx.x;
    int v = 0;
    if (t < 128) {
        v = (t < NB1) ? bsums[t] : 0;
        sd[t] = v;
    }
    __syncthreads();
    for (int off = 1; off < 128; off <<= 1) {
        int x = (t < 128 && t >= off) ? sd[t - off] : 0;
        __syncthreads();
        if (t < 128) sd[t] += x;
        __syncthreads();
    }
    if (t < 128) se[t] = sd[t] - v;   // exclusive
    __syncthreads();
    int gid = blockIdx.x * 256 + t;
    if (gid < N_NODES) row_start[gid] += se[gid >> 10];
    if (gid == 0) row_start[N_NODES] = N_EDGES;
}

// ---------------------------------------------------------------------------
// Fill CSR without atomics: position = row_start[dst] + rank (precomputed).
// ---------------------------------------------------------------------------
__global__ __launch_bounds__(256) void fill_csr(
    const int* __restrict__ src, const int* __restrict__ dst,
    const int* __restrict__ rank, const int* __restrict__ row_start,
    int* __restrict__ csr_src)
{
    int e = blockIdx.x * 256 + threadIdx.x;
    if (e >= N_EDGES) return;
    csr_src[row_start[dst[e]] + rank[e]] = src[e];
}

// ---------------------------------------------------------------------------
// Fused attention: one wave per dst node. lane l=h*8+d2 owns channels
// (h, 2d2, 2d2+1). Per edge: k = ushort (2 fp8) at s*640+256+2l,
// v = dword (2 bf16) at s*640+384+4l -> 384 B/edge (6 cache lines).
// 8-lane shfl_xor score reduce, online p-weighted accumulate. Unroll x4.
// NOTE: EDGE macro temps use unique names (fk0_/fk1_/ps_/p_) — R9 failed
// because `float k0 = cvt((int)k0,...)` self-shadowed the ushort argument
// and read uninitialized garbage (NaN). No atomics; max-shift skipped.
// ---------------------------------------------------------------------------
__global__ __launch_bounds__(256) void fused_attn(
    const char* __restrict__ qkvp, const int* __restrict__ row_start,
    const int* __restrict__ csr_src, ushort* __restrict__ attnb)
{
    int node = (blockIdx.x * 256 + threadIdx.x) >> 6;
    if (node >= N_NODES) return;
    int lane = threadIdx.x & 63;

    unsigned qb = *reinterpret_cast<const unsigned*>(
        qkvp + (size_t)node * 640 + lane * 4);
    float q0 = bf2f((ushort)qb), q1 = bf2f((ushort)(qb >> 16));

    int beg = row_start[node], end = row_start[node + 1];
    float denom = 0.f, a0 = 0.f, a1 = 0.f;
    const char* kbase = qkvp + 256 + lane * 2;
    const char* vbase = qkvp + 384 + lane * 4;

#define GATHER(s, kk, vv) { size_t go_ = (size_t)(s) * 640; \
        kk = *reinterpret_cast<const ushort*>(kbase + go_); \
        vv = *reinterpret_cast<const unsigned*>(vbase + go_); }
#define EDGE(kk, vv) { \
        float fk0_ = __builtin_amdgcn_cvt_f32_fp8((int)(kk), 0); \
        float fk1_ = __builtin_amdgcn_cvt_f32_fp8((int)(kk), 1); \
        float ps_ = fk0_ * q0 + fk1_ * q1; \
        ps_ += __shfl_xor(ps_, 1); \
        ps_ += __shfl_xor(ps_, 2); \
        ps_ += __shfl_xor(ps_, 4); \
        float p_ = __expf(ps_ * 0.25f); \
        denom += p_; \
        a0 += p_ * bf2f((ushort)(vv)); \
        a1 += p_ * bf2f((ushort)((vv) >> 16)); }

    int i = beg;
    for (; i + 4 <= end; i += 4) {
        int s0 = csr_src[i],     s1 = csr_src[i + 1];
        int s2 = csr_src[i + 2], s3 = csr_src[i + 3];
        ushort k0, k1, k2, k3;
        unsigned v0, v1, v2, v3;
        GATHER(s0, k0, v0); GATHER(s1, k1, v1);
        GATHER(s2, k2, v2); GATHER(s3, k3, v3);
        EDGE(k0, v0); EDGE(k1, v1); EDGE(k2, v2); EDGE(k3, v3);
    }
    for (; i < end; ++i) {
        int s = csr_src[i];
        ushort kk; unsigned vv;
        GATHER(s, kk, vv);
        EDGE(kk, vv);
    }
#undef GATHER
#undef EDGE

    float inv = (end > beg) ? 1.f / denom : 0.f;   // deg-0 node -> zeros
    unsigned o = ((unsigned)f2bf(a1 * inv) << 16) | (unsigned)f2bf(a0 * inv);
    *reinterpret_cast<unsigned*>(attnb + (size_t)node * 128 + lane * 2) = o;
}

// ---------------------------------------------------------------------------
// Workspace (bytes, 16B-aligned), total ~97 MB:
//   qkvp     [0,           64,000,000)   100000*640B [q bf16|k fp8|v bf16]
//   attnb    [64,000,000,  89,600,000)   100000*128 bf16
//   Wqb      [89,600,000,  89,698,304)   384*128 bf16 (permuted)
//   Wob      [89,698,304,  89,731,072)   128*128 bf16
//   bqp      [89,731,072,  89,732,608)   384 f32 (permuted)
//   counts   [89,732,608,  90,132,608)   400KB (memset 0)
//   rows     [90,132,608,  90,532,624)   N+1 ints (padded)
//   bsums    [90,532,624,  90,533,024)   98 ints (padded)
//   rank     [90,533,024,  93,733,024)   800K ints
//   csr_src  [93,733,024,  96,933,024)   800K ints
// ---------------------------------------------------------------------------
extern "C" void kernel_launch(void* const* d_in, const int* in_sizes, int n_in,
                              void* d_out, int out_size, void* d_ws, size_t ws_size,
                              hipStream_t stream) {
    const float* x     = (const float*)d_in[0];
    const float* W_qkv = (const float*)d_in[1];
    const float* b_qkv = (const float*)d_in[2];
    const float* W_out = (const float*)d_in[3];
    const float* b_out = (const float*)d_in[4];
    const int*   src   = (const int*)d_in[5];
    const int*   dst   = (const int*)d_in[6];
    float* out = (float*)d_out;

    char* w = (char*)d_ws;
    char*   qkvp     = w;
    ushort* attnb    = (ushort*)(w + 64000000);
    ushort* Wqb      = (ushort*)(w + 89600000);
    ushort* Wob      = (ushort*)(w + 89698304);
    float*  bqp      = (float*)(w + 89731072);
    int*    counts   = (int*)(w + 89732608);
    int*    row_start= (int*)(w + 90132608);
    int*    bsums    = (int*)(w + 90532624);
    int*    rank     = (int*)(w + 90533024);
    int*    csr_src  = (int*)(w + 93733024);

    hipMemsetAsync(counts, 0, 400000, stream);

    // weights permute + W_out cvt + dst histogram/rank (independent)
    prep_all<<<6762, 128, 0, stream>>>(W_qkv, b_qkv, W_out, dst,
                                       Wqb, bqp, Wob, counts, rank);

    // QKV projection: A = x fp32 (converted in staging), col-block fast
    gemm_mfma<1, 1><<<dim3(3, 782), 256, 0, stream>>>(
        (const void*)x, Wqb, bqp, (void*)qkvp, N_NODES, 0);

    scan1<<<NB1, 1024, 0, stream>>>(counts, row_start, bsums);
    scan23<<<391, 256, 0, stream>>>(bsums, row_start);
    fill_csr<<<3125, 256, 0, stream>>>(src, dst, rank, row_start, csr_src);

    fused_attn<<<25000, 256, 0, stream>>>(qkvp, row_start, csr_src, attnb);

    gemm_mfma<0, 0><<<dim3(1, 782), 256, 0, stream>>>(
        (const void*)attnb, Wob, b_out, (void*)out, N_NODES, 128);
}